// Round 3
// baseline (59.966 us; speedup 1.0000x reference)
//
#include <hip/hip_runtime.h>

// Neo-Hookean constants (match reference)
#define MU_C   3846.1538461538462f   // E/(2(1+nu))
#define LM_C   5769.2307692307695f   // E*nu/((1+nu)(1-2nu))
#define EPS_C  1e-10f

// B=4, N_QUAD=4, NPE=4 fixed by the reference problem.
#define ELB 64          // elements per block
#define SLAB 52         // padded floats per element slab in LDS (48 used; stride 208B -> bank stride 20 -> 2-way max)

// Transpose u (B, n_nodes, 3) -> ut (n_nodes, B, 4) padded float4 records.
__global__ __launch_bounds__(256) void nh_transpose_u_pad(
    const float* __restrict__ u, float4* __restrict__ ut, int n_nodes)
{
    const int i = blockIdx.x * 256 + threadIdx.x;
    if (i >= n_nodes) return;
    float4* q = ut + (size_t)i * 4;
    #pragma unroll
    for (int b = 0; b < 4; ++b) {
        const float* p = u + ((size_t)b * n_nodes + i) * 3;
        q[b] = make_float4(p[0], p[1], p[2], 0.f);
    }
}

// Thread t: element e_local = t>>2 (block covers 64 elements), batch b = t&3.
__global__ __launch_bounds__(256) void nh_partial_v3(
    const float* __restrict__ u,          // (4, n_nodes, 3)  fallback
    const float4* __restrict__ ut,        // (n_nodes, 4) padded float4
    const int*   __restrict__ elements,   // (n_elem, 4)
    const float* __restrict__ dN_dx,      // (n_elem, 4, 4, 3)
    const float* __restrict__ detJ,       // (n_elem, 4)
    const float* __restrict__ qw,         // (4,)
    float* __restrict__ partial,          // (gridDim.x, 4)
    int n_elem, int n_nodes, int use_ut)
{
    __shared__ float s_dn[ELB * SLAB];    // 13312 B
    __shared__ int   s_el[ELB * 4];       // 1024 B
    __shared__ float s_dj[ELB * 4];       // 1024 B
    __shared__ float s_red[4][4];

    const int t  = threadIdx.x;
    const int e0 = blockIdx.x * ELB;
    const int rem = min(ELB, n_elem - e0);

    // ---- stage dN_dx: rem*12 float4s, fully coalesced 1KB/instruction ----
    {
        const float4* src = reinterpret_cast<const float4*>(dN_dx) + (size_t)e0 * 12;
        const int nf4 = rem * 12;
        #pragma unroll
        for (int j = 0; j < 3; ++j) {
            const int m = t + 256 * j;
            if (m < nf4) {
                const float4 v = src[m];
                const int el = m / 12, ch = m % 12;
                *reinterpret_cast<float4*>(&s_dn[el * SLAB + ch * 4]) = v;
            }
        }
    }
    // ---- stage elements (wave 0) and detJ (wave 1), coalesced ----
    if (t < 64) {
        if (t < rem)
            reinterpret_cast<int4*>(s_el)[t] =
                reinterpret_cast<const int4*>(elements)[e0 + t];
    } else if (t < 128) {
        const int i = t - 64;
        if (i < rem)
            reinterpret_cast<float4*>(s_dj)[i] =
                reinterpret_cast<const float4*>(detJ)[e0 + i];
    }
    __syncthreads();

    const int el = t >> 2;
    const int b  = t & 3;
    float a = 0.f;

    if (el < rem) {
        // node indices (4-lane broadcast from LDS)
        const int4 nd = reinterpret_cast<const int4*>(s_el)[el];
        const int nodes[4] = {nd.x, nd.y, nd.z, nd.w};

        // gather u: one dwordx4 per node; the 4 batch-lanes cover one 64B line
        float eu[4][3];
        if (use_ut) {
            #pragma unroll
            for (int n = 0; n < 4; ++n) {
                const float4 v = ut[(size_t)nodes[n] * 4 + b];
                eu[n][0] = v.x; eu[n][1] = v.y; eu[n][2] = v.z;
            }
        } else {
            const float* ub = u + (size_t)b * n_nodes * 3;
            #pragma unroll
            for (int n = 0; n < 4; ++n) {
                const float* p = ub + (size_t)nodes[n] * 3;
                eu[n][0] = p[0]; eu[n][1] = p[1]; eu[n][2] = p[2];
            }
        }

        const float4 w4 = *reinterpret_cast<const float4*>(qw);
        const float* dj = &s_dj[el * 4];
        const float wq[4] = {dj[0] * w4.x, dj[1] * w4.y, dj[2] * w4.z, dj[3] * w4.w};

        const float* slab = &s_dn[el * SLAB];
        #pragma unroll
        for (int q = 0; q < 4; ++q) {
            // fragment for this q: 12 floats, three aligned ds_read_b128
            float4 f0 = *reinterpret_cast<const float4*>(slab + q * 12 + 0);
            float4 f1 = *reinterpret_cast<const float4*>(slab + q * 12 + 4);
            float4 f2 = *reinterpret_cast<const float4*>(slab + q * 12 + 8);
            float d[12] = {f0.x, f0.y, f0.z, f0.w, f1.x, f1.y, f1.z, f1.w,
                           f2.x, f2.y, f2.z, f2.w};
            // d[n*3 + j]

            float F[3][3];
            #pragma unroll
            for (int i = 0; i < 3; ++i) {
                #pragma unroll
                for (int j = 0; j < 3; ++j) {
                    float g = 0.f;
                    #pragma unroll
                    for (int n = 0; n < 4; ++n)
                        g = fmaf(eu[n][i], d[n * 3 + j], g);
                    F[i][j] = g + ((i == j) ? 1.f : 0.f);
                }
            }
            const float J =
                  F[0][0] * (F[1][1]*F[2][2] - F[1][2]*F[2][1])
                - F[0][1] * (F[1][0]*F[2][2] - F[1][2]*F[2][0])
                + F[0][2] * (F[1][0]*F[2][1] - F[1][1]*F[2][0]);

            float IC = 0.f;
            #pragma unroll
            for (int i = 0; i < 3; ++i)
                #pragma unroll
                for (int j = 0; j < 3; ++j)
                    IC = fmaf(F[i][j], F[i][j], IC);

            const float lj = __logf(fmaxf(J, EPS_C));
            const float W = 0.5f * MU_C * (IC - 3.f - 2.f * lj)
                          + 0.25f * LM_C * (fmaf(J, J, -1.f) - 2.f * lj);
            a = fmaf(W, wq[q], a);
        }
    }

    // reduce across lanes with same b (stride-4 groups)
    #pragma unroll
    for (int off = 32; off >= 4; off >>= 1)
        a += __shfl_down(a, off);
    // lanes 0..3 hold this wave's batch sums

    const int lane = t & 63;
    const int wid  = t >> 6;
    if (lane < 4) s_red[wid][lane] = a;
    __syncthreads();
    if (t < 4)
        partial[(size_t)blockIdx.x * 4 + t] =
            (s_red[0][t] + s_red[1][t]) + (s_red[2][t] + s_red[3][t]);
}

__global__ __launch_bounds__(256) void nh_final(
    const float* __restrict__ partial,  // (nparts, 4)
    float* __restrict__ out,            // (4,)
    int nparts)
{
    float accb[4] = {0.f, 0.f, 0.f, 0.f};
    for (int i = threadIdx.x; i < nparts; i += 256) {
        const float4 p = reinterpret_cast<const float4*>(partial)[i];
        accb[0] += p.x; accb[1] += p.y; accb[2] += p.z; accb[3] += p.w;
    }

    #pragma unroll
    for (int b = 0; b < 4; ++b) {
        float v = accb[b];
        #pragma unroll
        for (int off = 32; off > 0; off >>= 1)
            v += __shfl_down(v, off);
        accb[b] = v;
    }

    __shared__ float lds[4][4];
    const int lane = threadIdx.x & 63;
    const int wid  = threadIdx.x >> 6;
    if (lane == 0) {
        #pragma unroll
        for (int b = 0; b < 4; ++b) lds[wid][b] = accb[b];
    }
    __syncthreads();
    if (threadIdx.x == 0) {
        #pragma unroll
        for (int b = 0; b < 4; ++b)
            out[b] = (lds[0][b] + lds[1][b]) + (lds[2][b] + lds[3][b]);
    }
}

extern "C" void kernel_launch(void* const* d_in, const int* in_sizes, int n_in,
                              void* d_out, int out_size, void* d_ws, size_t ws_size,
                              hipStream_t stream) {
    const float* u        = (const float*)d_in[0];
    const int*   elements = (const int*)d_in[1];
    const float* dN_dx    = (const float*)d_in[2];
    const float* detJ     = (const float*)d_in[3];
    const float* qw       = (const float*)d_in[4];
    float* out = (float*)d_out;

    const int B       = out_size;            // 4
    const int n_nodes = in_sizes[0] / (3 * B);
    const int n_elem  = in_sizes[1] / 4;

    const int threads = 256;
    const int nblocks = (n_elem + ELB - 1) / ELB;

    const size_t ut_bytes      = (size_t)n_nodes * 4 * sizeof(float4);  // padded
    const size_t partial_bytes = (size_t)nblocks * 4 * sizeof(float);
    const int use_ut = (ws_size >= ut_bytes + partial_bytes) ? 1 : 0;

    float4* ut     = (float4*)d_ws;
    float* partial = use_ut ? (float*)((char*)d_ws + ut_bytes) : (float*)d_ws;

    if (use_ut) {
        const int tb = (n_nodes + threads - 1) / threads;
        nh_transpose_u_pad<<<tb, threads, 0, stream>>>(u, ut, n_nodes);
    }

    nh_partial_v3<<<nblocks, threads, 0, stream>>>(u, ut, elements, dN_dx, detJ, qw,
                                                   partial, n_elem, n_nodes, use_ut);
    nh_final<<<1, threads, 0, stream>>>(partial, out, nblocks);
}